// Round 13
// baseline (840.926 us; speedup 1.0000x reference)
//
#include <hip/hip_runtime.h>
#include <math.h>

#define NN   100000
#define EE   1600000
#define INF_ 64
#define HF   128
#define OUTF 3

#define TE    64
#define TN    64

typedef short  short8  __attribute__((ext_vector_type(8)));
typedef float  float4v __attribute__((ext_vector_type(4)));
typedef unsigned int uint4v __attribute__((ext_vector_type(4)));

// ---- B-fragment pack geometry (ushort counts) ----
#define L_M0  (8*3*64*8)     // msg W0: K=71->96, KC=3, N=128 -> 12288
#define L_M12 (8*4*64*8)     // msg W1/W2: KC=4, N=128 -> 16384
#define L_C0  (8*6*64*8)     // corr W0: K=192, KC=6, N=128 -> 24576
#define L_C12 (8*4*64*8)     // corr W1/W2 -> 16384
#define L_C3  (8*4*64*1)     // corr W3: K=128, N=3->16 -> 2048

#define OFF_M0H 0
#define OFF_M0L (OFF_M0H + L_M0)
#define OFF_M1H (OFF_M0L + L_M0)
#define OFF_M1L (OFF_M1H + L_M12)
#define OFF_M2H (OFF_M1L + L_M12)
#define OFF_M2L (OFF_M2H + L_M12)
#define OFF_C0H (OFF_M2L + L_M12)
#define OFF_C0L (OFF_C0H + L_C0)
#define OFF_C1H (OFF_C0L + L_C0)
#define OFF_C1L (OFF_C1H + L_C12)
#define OFF_C2H (OFF_C1L + L_C12)
#define OFF_C2L (OFF_C2H + L_C12)
#define OFF_C3H (OFF_C2L + L_C12)
#define OFF_C3L (OFF_C3H + L_C3)
#define FRAG_TOTAL (OFF_C3L + L_C3)      // 208896 ushorts = 417792 B
#define PREP_N (FRAG_TOTAL / 2)          // 104448 h-elements

// cumulative H-element boundaries for prep dispatch
#define CUM_M0 (L_M0)             // 12288
#define CUM_M1 (CUM_M0 + L_M12)   // 28672
#define CUM_M2 (CUM_M1 + L_M12)   // 45056
#define CUM_C0 (CUM_M2 + L_C0)    // 69632
#define CUM_C1 (CUM_C0 + L_C12)   // 86016
#define CUM_C2 (CUM_C1 + L_C12)   // 102400

__device__ __forceinline__ void atomic_fadd(float* p, float v) {
#if defined(__AMDGCN__)
    unsafeAtomicAdd(p, v);
#else
    atomicAdd(p, v);
#endif
}

__device__ __forceinline__ void split2(float v, unsigned short& h, unsigned short& l) {
    unsigned int bits = __float_as_uint(v);
    h = (unsigned short)(bits >> 16);
    float hf = __uint_as_float(bits & 0xffff0000u);
    l = (unsigned short)(__float_as_uint(v - hf) >> 16);
}

// pack hi-bf16 in high u16, lo-bf16 in low u16
__device__ __forceinline__ unsigned int pack_hl(float v) {
    unsigned int bits = __float_as_uint(v);
    float hf = __uint_as_float(bits & 0xffff0000u);
    unsigned int l = __float_as_uint(v - hf) >> 16;
    return (bits & 0xffff0000u) | l;
}

// 16B-chunk swizzle: spreads 16 lanes (rows) over 8 distinct 4-bank positions
// (2 lanes/bank = free). q is the 16B-chunk index within the row.
__device__ __forceinline__ int swz(int row, int q) {
    return q ^ ((row & 7) << 1) ^ ((row >> 3) & 1);
}

#define SEL_HI 0x07060302u
#define SEL_LO 0x05040100u
__device__ __forceinline__ short8 unpack8(uint4v a, uint4v b, unsigned int sel) {
    uint4v w;
    w[0] = __builtin_amdgcn_perm(a[1], a[0], sel);
    w[1] = __builtin_amdgcn_perm(a[3], a[2], sel);
    w[2] = __builtin_amdgcn_perm(b[1], b[0], sel);
    w[3] = __builtin_amdgcn_perm(b[3], b[2], sel);
    return *reinterpret_cast<short8*>(&w);
}

// ---------------- prep: pack all weights into per-lane MFMA B-fragments ----------------
__global__ void prep_kernel(const float* __restrict__ mW0, const float* __restrict__ mW1,
                            const float* __restrict__ mW2, const float* __restrict__ cW0,
                            const float* __restrict__ cW1, const float* __restrict__ cW2,
                            const float* __restrict__ cW3, unsigned short* __restrict__ frag)
{
    int t = blockIdx.x * 256 + threadIdx.x;
    if (t >= PREP_N) return;
    const float* W; int KC, Ktrue, Nld, Ntrue, offH, L, idx;
    if      (t < CUM_M0) { W=mW0; KC=3; Ktrue=71;  Nld=128; Ntrue=128; offH=OFF_M0H; L=L_M0;  idx=t; }
    else if (t < CUM_M1) { W=mW1; KC=4; Ktrue=128; Nld=128; Ntrue=128; offH=OFF_M1H; L=L_M12; idx=t-CUM_M0; }
    else if (t < CUM_M2) { W=mW2; KC=4; Ktrue=128; Nld=128; Ntrue=128; offH=OFF_M2H; L=L_M12; idx=t-CUM_M1; }
    else if (t < CUM_C0) { W=cW0; KC=6; Ktrue=192; Nld=128; Ntrue=128; offH=OFF_C0H; L=L_C0;  idx=t-CUM_M2; }
    else if (t < CUM_C1) { W=cW1; KC=4; Ktrue=128; Nld=128; Ntrue=128; offH=OFF_C1H; L=L_C12; idx=t-CUM_C0; }
    else if (t < CUM_C2) { W=cW2; KC=4; Ktrue=128; Nld=128; Ntrue=128; offH=OFF_C2H; L=L_C12; idx=t-CUM_C1; }
    else                 { W=cW3; KC=4; Ktrue=128; Nld=3;   Ntrue=3;   offH=OFF_C3H; L=L_C3;  idx=t-CUM_C2; }
    const int b    = idx & 7;
    const int lane = (idx >> 3) & 63;
    const int kc   = (idx >> 9) % KC;
    const int nt   = (idx >> 9) / KC;
    const int k = kc * 32 + (lane >> 4) * 8 + b;
    const int j = nt * 16 + (lane & 15);
    float v = (k < Ktrue && j < Ntrue) ? W[k * Nld + j] : 0.0f;
    unsigned short h, l;
    split2(v, h, l);
    frag[offH + idx]     = h;
    frag[offH + L + idx] = l;
}

// ---------------- shared MFMA layer machinery (packed-u32 LDS, 2x2 wave decomp) ----------------
// wave w: mh = w>>1 owns rows mh*32..+31; nh = w&1 owns cols nh*64..+63
template<int KC, int STRIDE>
__device__ __forceinline__ void layer_mm(float4v (&acc)[2][4],
    const unsigned int* Ahl,
    const unsigned short* __restrict__ Bh, const unsigned short* __restrict__ Bl,
    int lane, int w)
{
    const int g  = lane >> 4;
    const int lm = lane & 15;
    const int mh = w >> 1, nh = w & 1;
#pragma unroll
    for (int kc = 0; kc < KC; ++kc) {
        short8 bh[4], bl[4], ah[2], al[2];
#pragma unroll
        for (int n = 0; n < 4; ++n) {
            const int nt = nh * 4 + n;
            const size_t off = ((size_t)(nt * KC + kc) * 64 + lane) * 8;
            bh[n] = *reinterpret_cast<const short8*>(Bh + off);
            bl[n] = *reinterpret_cast<const short8*>(Bl + off);
        }
#pragma unroll
        for (int m = 0; m < 2; ++m) {
            const int row = mh * 32 + m * 16 + lm;
            const int q0  = (kc * 4 + g) * 2;
            uint4v a = *reinterpret_cast<const uint4v*>(Ahl + row * STRIDE + (swz(row, q0)     << 2));
            uint4v b = *reinterpret_cast<const uint4v*>(Ahl + row * STRIDE + (swz(row, q0 + 1) << 2));
            ah[m] = unpack8(a, b, SEL_HI);
            al[m] = unpack8(a, b, SEL_LO);
        }
#pragma unroll
        for (int m = 0; m < 2; ++m)
#pragma unroll
            for (int n = 0; n < 4; ++n) {
                acc[m][n] = __builtin_amdgcn_mfma_f32_16x16x32_bf16(ah[m], bh[n], acc[m][n], 0, 0, 0);
                acc[m][n] = __builtin_amdgcn_mfma_f32_16x16x32_bf16(al[m], bh[n], acc[m][n], 0, 0, 0);
                acc[m][n] = __builtin_amdgcn_mfma_f32_16x16x32_bf16(ah[m], bl[n], acc[m][n], 0, 0, 0);
            }
    }
}

template<int STRIDE>
__device__ __forceinline__ void write_back(float4v (&acc)[2][4],
    unsigned int* Ahl, const float* __restrict__ bias, int lane, int w)
{
    const int g = lane >> 4, lm = lane & 15;
    const int mh = w >> 1, nh = w & 1;
    float bv[4];
#pragma unroll
    for (int n = 0; n < 4; ++n) bv[n] = bias[nh * 64 + n * 16 + lm];
#pragma unroll
    for (int m = 0; m < 2; ++m)
#pragma unroll
        for (int n = 0; n < 4; ++n) {
            const int c = nh * 64 + n * 16 + lm;
#pragma unroll
            for (int r = 0; r < 4; ++r) {
                const int row = mh * 32 + m * 16 + g * 4 + r;
                float v = fmaxf(acc[m][n][r] + bv[n], 0.0f);
                Ahl[row * STRIDE + (swz(row, c >> 2) << 2) + (c & 3)] = pack_hl(v);
            }
        }
}

// ---------------- edge kernel ----------------
__global__ __launch_bounds__(256, 4) void edge_kernel(
    const float* __restrict__ x, const int* __restrict__ ei,
    const unsigned short* __restrict__ frag,
    const float* __restrict__ b0, const float* __restrict__ b1, const float* __restrict__ b2,
    float* __restrict__ agg)
{
    __shared__ unsigned int Ahl[64 * 128];
    __shared__ int ridx[TE];
    const int tid  = threadIdx.x;
    const int lane = tid & 63;
    const int w    = tid >> 6;
    const int e0   = blockIdx.x * TE;

    // stage x[row] (cols 0..63) packed; thread (e, t) writes chunks 4t..4t+3
    {
        const int e = tid >> 2, t = tid & 3;
        const int r = ei[e0 + e];
        if (t == 0) ridx[e] = r;
        const float4* xr = reinterpret_cast<const float4*>(x + (size_t)r * INF_) + t * 4;
#pragma unroll
        for (int u = 0; u < 4; ++u) {
            float4 f = xr[u];
            const int ch = 4 * t + u;
            *reinterpret_cast<uint4v*>(&Ahl[e * 128 + (swz(e, ch) << 2)]) =
                uint4v{pack_hl(f.x), pack_hl(f.y), pack_hl(f.z), pack_hl(f.w)};
        }
    }

    // edge features cols 64..71 (chunks 16,17) + zero pad chunks 18..23 (cols 72..95)
    if (tid < TE) {
        const int e = tid;
        const int r = ei[e0 + e];
        const int c = ei[EE + e0 + e];
        const float* xr = x + (size_t)r * INF_;
        const float* xc = x + (size_t)c * INF_;
        float r0 = xc[0] - xr[0];
        float r1 = xc[1] - xr[1];
        float r2 = xc[2] - xr[2];
        float d  = sqrtf(fmaf(r0, r0, fmaf(r1, r1, r2 * r2))) + 1e-12f;
        float iv = 1.0f / d;
        *reinterpret_cast<uint4v*>(&Ahl[e * 128 + (swz(e, 16) << 2)]) =
            uint4v{pack_hl(r0), pack_hl(r1), pack_hl(r2), pack_hl(d)};
        *reinterpret_cast<uint4v*>(&Ahl[e * 128 + (swz(e, 17) << 2)]) =
            uint4v{pack_hl(r0 * iv), pack_hl(r1 * iv), pack_hl(r2 * iv), 0u};
        uint4v z = {0, 0, 0, 0};
#pragma unroll
        for (int ch = 18; ch < 24; ++ch)
            *reinterpret_cast<uint4v*>(&Ahl[e * 128 + (swz(e, ch) << 2)]) = z;
    }
    __syncthreads();

    float4v acc[2][4];

#pragma unroll
    for (int m = 0; m < 2; ++m) for (int n = 0; n < 4; ++n) acc[m][n] = (float4v)0.0f;
    layer_mm<3, 128>(acc, Ahl, frag + OFF_M0H, frag + OFF_M0L, lane, w);
    __syncthreads();
    write_back<128>(acc, Ahl, b0, lane, w);
    __syncthreads();

#pragma unroll
    for (int m = 0; m < 2; ++m) for (int n = 0; n < 4; ++n) acc[m][n] = (float4v)0.0f;
    layer_mm<4, 128>(acc, Ahl, frag + OFF_M1H, frag + OFF_M1L, lane, w);
    __syncthreads();
    write_back<128>(acc, Ahl, b1, lane, w);
    __syncthreads();

#pragma unroll
    for (int m = 0; m < 2; ++m) for (int n = 0; n < 4; ++n) acc[m][n] = (float4v)0.0f;
    layer_mm<4, 128>(acc, Ahl, frag + OFF_M2H, frag + OFF_M2L, lane, w);

    // bias + relu + coalesced atomic scatter straight from accumulators:
    // per instruction 4 rows x 16 consecutive cols (64B/row-segment, no sector amp)
    {
        const int g = lane >> 4, lm = lane & 15;
        const int mh = w >> 1, nh = w & 1;
        float bv[4];
#pragma unroll
        for (int n = 0; n < 4; ++n) bv[n] = b2[nh * 64 + n * 16 + lm];
#pragma unroll
        for (int m = 0; m < 2; ++m)
#pragma unroll
            for (int r = 0; r < 4; ++r) {
                const int rl = mh * 32 + m * 16 + g * 4 + r;
                float* base = agg + (size_t)ridx[rl] * HF + nh * 64 + lm;
#pragma unroll
                for (int n = 0; n < 4; ++n) {
                    float v = fmaxf(acc[m][n][r] + bv[n], 0.0f);
                    atomic_fadd(base + n * 16, v);
                }
            }
    }
}

// ---------------- node kernel (MFMA) ----------------
__global__ __launch_bounds__(256, 3) void node_mfma(
    const float* __restrict__ x, const float* __restrict__ agg,
    const unsigned short* __restrict__ frag,
    const float* __restrict__ cb0, const float* __restrict__ cb1,
    const float* __restrict__ cb2, const float* __restrict__ cb3,
    float* __restrict__ out)
{
    __shared__ unsigned int Ahl[64 * 192];   // 48 KB
    const int tid  = threadIdx.x;
    const int lane = tid & 63;
    const int w    = tid >> 6;
    const int n0   = blockIdx.x * TN;

    // stage concat(x, agg) packed: thread (e, t) writes 6 x 2 chunks
    {
        const int e = tid >> 2, t = tid & 3;
        const int gn = n0 + e;
        const int gs = (gn < NN) ? gn : (NN - 1);
#pragma unroll
        for (int ss = 0; ss < 6; ++ss) {
            const int s  = t * 6 + ss;       // 8-u32 slot 0..23
            const int c0 = s * 8;
            const float* src = (c0 < INF_) ? (x + (size_t)gs * INF_ + c0)
                                           : (agg + (size_t)gs * HF + (c0 - INF_));
            float4 f0 = *reinterpret_cast<const float4*>(src);
            float4 f1 = *reinterpret_cast<const float4*>(src + 4);
            const int ch = s * 2;
            *reinterpret_cast<uint4v*>(&Ahl[e * 192 + (swz(e, ch) << 2)]) =
                uint4v{pack_hl(f0.x), pack_hl(f0.y), pack_hl(f0.z), pack_hl(f0.w)};
            *reinterpret_cast<uint4v*>(&Ahl[e * 192 + (swz(e, ch + 1) << 2)]) =
                uint4v{pack_hl(f1.x), pack_hl(f1.y), pack_hl(f1.z), pack_hl(f1.w)};
        }
    }
    __syncthreads();

    float4v acc[2][4];

#pragma unroll
    for (int m = 0; m < 2; ++m) for (int n = 0; n < 4; ++n) acc[m][n] = (float4v)0.0f;
    layer_mm<6, 192>(acc, Ahl, frag + OFF_C0H, frag + OFF_C0L, lane, w);
    __syncthreads();
    write_back<192>(acc, Ahl, cb0, lane, w);
    __syncthreads();

#pragma unroll
    for (int m = 0; m < 2; ++m) for (int n = 0; n < 4; ++n) acc[m][n] = (float4v)0.0f;
    layer_mm<4, 192>(acc, Ahl, frag + OFF_C1H, frag + OFF_C1L, lane, w);
    __syncthreads();
    write_back<192>(acc, Ahl, cb1, lane, w);
    __syncthreads();

#pragma unroll
    for (int m = 0; m < 2; ++m) for (int n = 0; n < 4; ++n) acc[m][n] = (float4v)0.0f;
    layer_mm<4, 192>(acc, Ahl, frag + OFF_C2H, frag + OFF_C2L, lane, w);
    __syncthreads();
    write_back<192>(acc, Ahl, cb2, lane, w);
    __syncthreads();

    // tail 128 -> 3 (padded to 16 cols): wave w owns rows w*16..w*16+15
    {
        const int g = lane >> 4, lm = lane & 15;
        float4v acc3 = {0.0f, 0.0f, 0.0f, 0.0f};
#pragma unroll
        for (int kc = 0; kc < 4; ++kc) {
            const size_t off = ((size_t)kc * 64 + lane) * 8;
            short8 bh = *reinterpret_cast<const short8*>(frag + OFF_C3H + off);
            short8 bl = *reinterpret_cast<const short8*>(frag + OFF_C3L + off);
            const int row = w * 16 + lm;
            const int q0  = (kc * 4 + g) * 2;
            uint4v a = *reinterpret_cast<const uint4v*>(Ahl + row * 192 + (swz(row, q0)     << 2));
            uint4v b = *reinterpret_cast<const uint4v*>(Ahl + row * 192 + (swz(row, q0 + 1) << 2));
            short8 ah = unpack8(a, b, SEL_HI);
            short8 al = unpack8(a, b, SEL_LO);
            acc3 = __builtin_amdgcn_mfma_f32_16x16x32_bf16(ah, bh, acc3, 0, 0, 0);
            acc3 = __builtin_amdgcn_mfma_f32_16x16x32_bf16(al, bh, acc3, 0, 0, 0);
            acc3 = __builtin_amdgcn_mfma_f32_16x16x32_bf16(ah, bl, acc3, 0, 0, 0);
        }
        if (lm < OUTF) {
            const float bo = cb3[lm];
#pragma unroll
            for (int r = 0; r < 4; ++r) {
                const int gn = n0 + w * 16 + g * 4 + r;
                if (gn < NN) out[(size_t)gn * OUTF + lm] = acc3[r] + bo;
            }
        }
    }
}

extern "C" void kernel_launch(void* const* d_in, const int* in_sizes, int n_in,
                              void* d_out, int out_size, void* d_ws, size_t ws_size,
                              hipStream_t stream)
{
    const float* x   = (const float*)d_in[0];
    const int*   ei  = (const int*)  d_in[1];
    const float* mW0 = (const float*)d_in[2];
    const float* mb0 = (const float*)d_in[3];
    const float* mW1 = (const float*)d_in[4];
    const float* mb1 = (const float*)d_in[5];
    const float* mW2 = (const float*)d_in[6];
    const float* mb2 = (const float*)d_in[7];
    const float* cW0 = (const float*)d_in[8];
    const float* cb0 = (const float*)d_in[9];
    const float* cW1 = (const float*)d_in[10];
    const float* cb1 = (const float*)d_in[11];
    const float* cW2 = (const float*)d_in[12];
    const float* cb2 = (const float*)d_in[13];
    const float* cW3 = (const float*)d_in[14];
    const float* cb3 = (const float*)d_in[15];
    float* agg = (float*)d_ws;
    float* out = (float*)d_out;

    const size_t AGG_BYTES  = (size_t)NN * HF * sizeof(float);
    const size_t FRAG_BYTES = (size_t)FRAG_TOTAL * sizeof(unsigned short);
    unsigned short* frag = (unsigned short*)((char*)d_ws + AGG_BYTES);
    (void)FRAG_BYTES;

    hipMemsetAsync(agg, 0, AGG_BYTES, stream);
    prep_kernel<<<(PREP_N + 255) / 256, 256, 0, stream>>>(mW0, mW1, mW2, cW0, cW1, cW2, cW3, frag);
    edge_kernel<<<EE / TE, 256, 0, stream>>>(x, ei, frag, mb0, mb1, mb2, agg);
    node_mfma<<<(NN + TN - 1) / TN, 256, 0, stream>>>(x, agg, frag, cb0, cb1, cb2, cb3, out);
}

// Round 14
// 805.136 us; speedup vs baseline: 1.0445x; 1.0445x over previous
//
#include <hip/hip_runtime.h>
#include <math.h>

#define NN   100000
#define EE   1600000
#define INF_ 64
#define HF   128
#define OUTF 3

#define TE    64
#define TN    64

typedef short  short8  __attribute__((ext_vector_type(8)));
typedef float  float4v __attribute__((ext_vector_type(4)));
typedef unsigned int uint4v __attribute__((ext_vector_type(4)));

// ---- B-fragment pack geometry (ushort counts) ----
#define L_M0  (8*3*64*8)     // msg W0: K=71->96, KC=3, N=128 -> 12288
#define L_M12 (8*4*64*8)     // msg W1/W2: KC=4, N=128 -> 16384
#define L_C0  (8*6*64*8)     // corr W0: K=192, KC=6, N=128 -> 24576
#define L_C12 (8*4*64*8)     // corr W1/W2 -> 16384
#define L_C3  (8*4*64*1)     // corr W3: K=128, N=3->16 -> 2048

#define OFF_M0H 0
#define OFF_M0L (OFF_M0H + L_M0)
#define OFF_M1H (OFF_M0L + L_M0)
#define OFF_M1L (OFF_M1H + L_M12)
#define OFF_M2H (OFF_M1L + L_M12)
#define OFF_M2L (OFF_M2H + L_M12)
#define OFF_C0H (OFF_M2L + L_M12)
#define OFF_C0L (OFF_C0H + L_C0)
#define OFF_C1H (OFF_C0L + L_C0)
#define OFF_C1L (OFF_C1H + L_C12)
#define OFF_C2H (OFF_C1L + L_C12)
#define OFF_C2L (OFF_C2H + L_C12)
#define OFF_C3H (OFF_C2L + L_C12)
#define OFF_C3L (OFF_C3H + L_C3)
#define FRAG_TOTAL (OFF_C3L + L_C3)      // 208896 ushorts = 417792 B
#define PREP_N (FRAG_TOTAL / 2)          // 104448 h-elements

// cumulative H-element boundaries for prep dispatch
#define CUM_M0 (L_M0)             // 12288
#define CUM_M1 (CUM_M0 + L_M12)   // 28672
#define CUM_M2 (CUM_M1 + L_M12)   // 45056
#define CUM_C0 (CUM_M2 + L_C0)    // 69632
#define CUM_C1 (CUM_C0 + L_C12)   // 86016
#define CUM_C2 (CUM_C1 + L_C12)   // 102400

__device__ __forceinline__ void atomic_fadd(float* p, float v) {
#if defined(__AMDGCN__)
    unsafeAtomicAdd(p, v);
#else
    atomicAdd(p, v);
#endif
}

__device__ __forceinline__ void split2(float v, unsigned short& h, unsigned short& l) {
    unsigned int bits = __float_as_uint(v);
    h = (unsigned short)(bits >> 16);
    float hf = __uint_as_float(bits & 0xffff0000u);
    l = (unsigned short)(__float_as_uint(v - hf) >> 16);
}

// pack hi-bf16 in high u16, lo-bf16 in low u16
__device__ __forceinline__ unsigned int pack_hl(float v) {
    unsigned int bits = __float_as_uint(v);
    float hf = __uint_as_float(bits & 0xffff0000u);
    unsigned int l = __float_as_uint(v - hf) >> 16;
    return (bits & 0xffff0000u) | l;
}

// 16B-chunk swizzle (verified r13: conflicts 5.28e7 -> 1.76e7).
// q = 16B-chunk index within the row; flips only low 4 bits of q.
__device__ __forceinline__ int swz(int row, int q) {
    return q ^ ((row & 7) << 1) ^ ((row >> 3) & 1);
}

#define SEL_HI 0x07060302u
#define SEL_LO 0x05040100u
__device__ __forceinline__ short8 unpack8(uint4v a, uint4v b, unsigned int sel) {
    uint4v w;
    w[0] = __builtin_amdgcn_perm(a[1], a[0], sel);
    w[1] = __builtin_amdgcn_perm(a[3], a[2], sel);
    w[2] = __builtin_amdgcn_perm(b[1], b[0], sel);
    w[3] = __builtin_amdgcn_perm(b[3], b[2], sel);
    return *reinterpret_cast<short8*>(&w);
}

// ---------------- prep: pack all weights into per-lane MFMA B-fragments ----------------
__global__ void prep_kernel(const float* __restrict__ mW0, const float* __restrict__ mW1,
                            const float* __restrict__ mW2, const float* __restrict__ cW0,
                            const float* __restrict__ cW1, const float* __restrict__ cW2,
                            const float* __restrict__ cW3, unsigned short* __restrict__ frag)
{
    int t = blockIdx.x * 256 + threadIdx.x;
    if (t >= PREP_N) return;
    const float* W; int KC, Ktrue, Nld, Ntrue, offH, L, idx;
    if      (t < CUM_M0) { W=mW0; KC=3; Ktrue=71;  Nld=128; Ntrue=128; offH=OFF_M0H; L=L_M0;  idx=t; }
    else if (t < CUM_M1) { W=mW1; KC=4; Ktrue=128; Nld=128; Ntrue=128; offH=OFF_M1H; L=L_M12; idx=t-CUM_M0; }
    else if (t < CUM_M2) { W=mW2; KC=4; Ktrue=128; Nld=128; Ntrue=128; offH=OFF_M2H; L=L_M12; idx=t-CUM_M1; }
    else if (t < CUM_C0) { W=cW0; KC=6; Ktrue=192; Nld=128; Ntrue=128; offH=OFF_C0H; L=L_C0;  idx=t-CUM_M2; }
    else if (t < CUM_C1) { W=cW1; KC=4; Ktrue=128; Nld=128; Ntrue=128; offH=OFF_C1H; L=L_C12; idx=t-CUM_C0; }
    else if (t < CUM_C2) { W=cW2; KC=4; Ktrue=128; Nld=128; Ntrue=128; offH=OFF_C2H; L=L_C12; idx=t-CUM_C1; }
    else                 { W=cW3; KC=4; Ktrue=128; Nld=3;   Ntrue=3;   offH=OFF_C3H; L=L_C3;  idx=t-CUM_C2; }
    const int b    = idx & 7;
    const int lane = (idx >> 3) & 63;
    const int kc   = (idx >> 9) % KC;
    const int nt   = (idx >> 9) / KC;
    const int k = kc * 32 + (lane >> 4) * 8 + b;
    const int j = nt * 16 + (lane & 15);
    float v = (k < Ktrue && j < Ntrue) ? W[k * Nld + j] : 0.0f;
    unsigned short h, l;
    split2(v, h, l);
    frag[offH + idx]     = h;
    frag[offH + L + idx] = l;
}

// ---------------- shared MFMA layer machinery ----------------
// r12 decomposition (full-M per wave, 2 n-tiles: B-L2 traffic 180 KB/block)
// + r13 swizzle (conflict-free A reads). acc[4][2].
template<int KC, int STRIDE>
__device__ __forceinline__ void layer_mm(float4v (&acc)[4][2],
    const unsigned int* Ahl,
    const unsigned short* __restrict__ Bh, const unsigned short* __restrict__ Bl,
    int lane, int w)
{
    const int g  = lane >> 4;
    const int lm = lane & 15;
#pragma unroll
    for (int kc = 0; kc < KC; ++kc) {
        short8 bh[2], bl[2], ah[4], al[4];
#pragma unroll
        for (int n = 0; n < 2; ++n) {
            const int nt = 2 * w + n;
            const size_t off = ((size_t)(nt * KC + kc) * 64 + lane) * 8;
            bh[n] = *reinterpret_cast<const short8*>(Bh + off);
            bl[n] = *reinterpret_cast<const short8*>(Bl + off);
        }
#pragma unroll
        for (int m = 0; m < 4; ++m) {
            const int row = m * 16 + lm;
            const int q0  = (kc * 4 + g) * 2;
            uint4v a = *reinterpret_cast<const uint4v*>(Ahl + row * STRIDE + (swz(row, q0)     << 2));
            uint4v b = *reinterpret_cast<const uint4v*>(Ahl + row * STRIDE + (swz(row, q0 + 1) << 2));
            ah[m] = unpack8(a, b, SEL_HI);
            al[m] = unpack8(a, b, SEL_LO);
        }
#pragma unroll
        for (int m = 0; m < 4; ++m)
#pragma unroll
            for (int n = 0; n < 2; ++n) {
                acc[m][n] = __builtin_amdgcn_mfma_f32_16x16x32_bf16(ah[m], bh[n], acc[m][n], 0, 0, 0);
                acc[m][n] = __builtin_amdgcn_mfma_f32_16x16x32_bf16(al[m], bh[n], acc[m][n], 0, 0, 0);
                acc[m][n] = __builtin_amdgcn_mfma_f32_16x16x32_bf16(ah[m], bl[n], acc[m][n], 0, 0, 0);
            }
    }
}

template<int STRIDE>
__device__ __forceinline__ void write_back(float4v (&acc)[4][2],
    unsigned int* Ahl, const float* __restrict__ bias, int lane, int w)
{
    const int g = lane >> 4, lm = lane & 15;
    float bv0 = bias[w * 32 + lm];
    float bv1 = bias[w * 32 + 16 + lm];
#pragma unroll
    for (int m = 0; m < 4; ++m)
#pragma unroll
        for (int n = 0; n < 2; ++n) {
            const float bv = (n == 0) ? bv0 : bv1;
            const int c = w * 32 + n * 16 + lm;
#pragma unroll
            for (int r = 0; r < 4; ++r) {
                const int row = m * 16 + g * 4 + r;
                float v = fmaxf(acc[m][n][r] + bv, 0.0f);
                Ahl[row * STRIDE + (swz(row, c >> 2) << 2) + (c & 3)] = pack_hl(v);
            }
        }
}

// ---------------- edge kernel ----------------
__global__ __launch_bounds__(256, 4) void edge_kernel(
    const float* __restrict__ x, const int* __restrict__ ei,
    const unsigned short* __restrict__ frag,
    const float* __restrict__ b0, const float* __restrict__ b1, const float* __restrict__ b2,
    float* __restrict__ agg)
{
    __shared__ unsigned int Ahl[64 * 128];
    __shared__ int ridx[TE];
    const int tid  = threadIdx.x;
    const int lane = tid & 63;
    const int w    = tid >> 6;
    const int e0   = blockIdx.x * TE;

    // stage x[row] (cols 0..63) packed; thread (e, t) writes chunks 4t..4t+3
    {
        const int e = tid >> 2, t = tid & 3;
        const int r = ei[e0 + e];
        if (t == 0) ridx[e] = r;
        const float4* xr = reinterpret_cast<const float4*>(x + (size_t)r * INF_) + t * 4;
#pragma unroll
        for (int u = 0; u < 4; ++u) {
            float4 f = xr[u];
            const int ch = 4 * t + u;
            *reinterpret_cast<uint4v*>(&Ahl[e * 128 + (swz(e, ch) << 2)]) =
                uint4v{pack_hl(f.x), pack_hl(f.y), pack_hl(f.z), pack_hl(f.w)};
        }
    }

    // edge features cols 64..71 (chunks 16,17) + zero pad chunks 18..23 (cols 72..95)
    if (tid < TE) {
        const int e = tid;
        const int r = ei[e0 + e];
        const int c = ei[EE + e0 + e];
        const float* xr = x + (size_t)r * INF_;
        const float* xc = x + (size_t)c * INF_;
        float r0 = xc[0] - xr[0];
        float r1 = xc[1] - xr[1];
        float r2 = xc[2] - xr[2];
        float d  = sqrtf(fmaf(r0, r0, fmaf(r1, r1, r2 * r2))) + 1e-12f;
        float iv = 1.0f / d;
        *reinterpret_cast<uint4v*>(&Ahl[e * 128 + (swz(e, 16) << 2)]) =
            uint4v{pack_hl(r0), pack_hl(r1), pack_hl(r2), pack_hl(d)};
        *reinterpret_cast<uint4v*>(&Ahl[e * 128 + (swz(e, 17) << 2)]) =
            uint4v{pack_hl(r0 * iv), pack_hl(r1 * iv), pack_hl(r2 * iv), 0u};
        uint4v z = {0, 0, 0, 0};
#pragma unroll
        for (int ch = 18; ch < 24; ++ch)
            *reinterpret_cast<uint4v*>(&Ahl[e * 128 + (swz(e, ch) << 2)]) = z;
    }
    __syncthreads();

    float4v acc[4][2];

#pragma unroll
    for (int m = 0; m < 4; ++m) for (int n = 0; n < 2; ++n) acc[m][n] = (float4v)0.0f;
    layer_mm<3, 128>(acc, Ahl, frag + OFF_M0H, frag + OFF_M0L, lane, w);
    __syncthreads();
    write_back<128>(acc, Ahl, b0, lane, w);
    __syncthreads();

#pragma unroll
    for (int m = 0; m < 4; ++m) for (int n = 0; n < 2; ++n) acc[m][n] = (float4v)0.0f;
    layer_mm<4, 128>(acc, Ahl, frag + OFF_M1H, frag + OFF_M1L, lane, w);
    __syncthreads();
    write_back<128>(acc, Ahl, b1, lane, w);
    __syncthreads();

#pragma unroll
    for (int m = 0; m < 4; ++m) for (int n = 0; n < 2; ++n) acc[m][n] = (float4v)0.0f;
    layer_mm<4, 128>(acc, Ahl, frag + OFF_M2H, frag + OFF_M2L, lane, w);

    // bias + relu + coalesced atomic scatter straight from accumulators:
    // per instruction 4 rows x 16 consecutive cols (64B/row-segment, no sector amp)
    {
        const int g = lane >> 4, lm = lane & 15;
        float bv0 = b2[w * 32 + lm];
        float bv1 = b2[w * 32 + 16 + lm];
#pragma unroll
        for (int m = 0; m < 4; ++m)
#pragma unroll
            for (int r = 0; r < 4; ++r) {
                const int rl = m * 16 + g * 4 + r;
                float* base = agg + (size_t)ridx[rl] * HF;
                float v0 = fmaxf(acc[m][0][r] + bv0, 0.0f);
                float v1 = fmaxf(acc[m][1][r] + bv1, 0.0f);
                atomic_fadd(base + w * 32 + lm,      v0);
                atomic_fadd(base + w * 32 + 16 + lm, v1);
            }
    }
}

// ---------------- node kernel (MFMA) ----------------
__global__ __launch_bounds__(256, 3) void node_mfma(
    const float* __restrict__ x, const float* __restrict__ agg,
    const unsigned short* __restrict__ frag,
    const float* __restrict__ cb0, const float* __restrict__ cb1,
    const float* __restrict__ cb2, const float* __restrict__ cb3,
    float* __restrict__ out)
{
    __shared__ unsigned int Ahl[64 * 192];   // 48 KB
    const int tid  = threadIdx.x;
    const int lane = tid & 63;
    const int w    = tid >> 6;
    const int n0   = blockIdx.x * TN;

    // stage concat(x, agg) packed: thread (e, t) writes 6 x 2 chunks
    {
        const int e = tid >> 2, t = tid & 3;
        const int gn = n0 + e;
        const int gs = (gn < NN) ? gn : (NN - 1);
#pragma unroll
        for (int ss = 0; ss < 6; ++ss) {
            const int s  = t * 6 + ss;       // 8-u32 slot 0..23
            const int c0 = s * 8;
            const float* src = (c0 < INF_) ? (x + (size_t)gs * INF_ + c0)
                                           : (agg + (size_t)gs * HF + (c0 - INF_));
            float4 f0 = *reinterpret_cast<const float4*>(src);
            float4 f1 = *reinterpret_cast<const float4*>(src + 4);
            const int ch = s * 2;
            *reinterpret_cast<uint4v*>(&Ahl[e * 192 + (swz(e, ch) << 2)]) =
                uint4v{pack_hl(f0.x), pack_hl(f0.y), pack_hl(f0.z), pack_hl(f0.w)};
            *reinterpret_cast<uint4v*>(&Ahl[e * 192 + (swz(e, ch + 1) << 2)]) =
                uint4v{pack_hl(f1.x), pack_hl(f1.y), pack_hl(f1.z), pack_hl(f1.w)};
        }
    }
    __syncthreads();

    float4v acc[4][2];

#pragma unroll
    for (int m = 0; m < 4; ++m) for (int n = 0; n < 2; ++n) acc[m][n] = (float4v)0.0f;
    layer_mm<6, 192>(acc, Ahl, frag + OFF_C0H, frag + OFF_C0L, lane, w);
    __syncthreads();
    write_back<192>(acc, Ahl, cb0, lane, w);
    __syncthreads();

#pragma unroll
    for (int m = 0; m < 4; ++m) for (int n = 0; n < 2; ++n) acc[m][n] = (float4v)0.0f;
    layer_mm<4, 192>(acc, Ahl, frag + OFF_C1H, frag + OFF_C1L, lane, w);
    __syncthreads();
    write_back<192>(acc, Ahl, cb1, lane, w);
    __syncthreads();

#pragma unroll
    for (int m = 0; m < 4; ++m) for (int n = 0; n < 2; ++n) acc[m][n] = (float4v)0.0f;
    layer_mm<4, 192>(acc, Ahl, frag + OFF_C2H, frag + OFF_C2L, lane, w);
    __syncthreads();
    write_back<192>(acc, Ahl, cb2, lane, w);
    __syncthreads();

    // tail 128 -> 3 (padded to 16 cols): wave w owns rows w*16..w*16+15
    {
        const int g = lane >> 4, lm = lane & 15;
        float4v acc3 = {0.0f, 0.0f, 0.0f, 0.0f};
#pragma unroll
        for (int kc = 0; kc < 4; ++kc) {
            const size_t off = ((size_t)kc * 64 + lane) * 8;
            short8 bh = *reinterpret_cast<const short8*>(frag + OFF_C3H + off);
            short8 bl = *reinterpret_cast<const short8*>(frag + OFF_C3L + off);
            const int row = w * 16 + lm;
            const int q0  = (kc * 4 + g) * 2;
            uint4v a = *reinterpret_cast<const uint4v*>(Ahl + row * 192 + (swz(row, q0)     << 2));
            uint4v b = *reinterpret_cast<const uint4v*>(Ahl + row * 192 + (swz(row, q0 + 1) << 2));
            short8 ah = unpack8(a, b, SEL_HI);
            short8 al = unpack8(a, b, SEL_LO);
            acc3 = __builtin_amdgcn_mfma_f32_16x16x32_bf16(ah, bh, acc3, 0, 0, 0);
            acc3 = __builtin_amdgcn_mfma_f32_16x16x32_bf16(al, bh, acc3, 0, 0, 0);
            acc3 = __builtin_amdgcn_mfma_f32_16x16x32_bf16(ah, bl, acc3, 0, 0, 0);
        }
        if (lm < OUTF) {
            const float bo = cb3[lm];
#pragma unroll
            for (int r = 0; r < 4; ++r) {
                const int gn = n0 + w * 16 + g * 4 + r;
                if (gn < NN) out[(size_t)gn * OUTF + lm] = acc3[r] + bo;
            }
        }
    }
}

extern "C" void kernel_launch(void* const* d_in, const int* in_sizes, int n_in,
                              void* d_out, int out_size, void* d_ws, size_t ws_size,
                              hipStream_t stream)
{
    const float* x   = (const float*)d_in[0];
    const int*   ei  = (const int*)  d_in[1];
    const float* mW0 = (const float*)d_in[2];
    const float* mb0 = (const float*)d_in[3];
    const float* mW1 = (const float*)d_in[4];
    const float* mb1 = (const float*)d_in[5];
    const float* mW2 = (const float*)d_in[6];
    const float* mb2 = (const float*)d_in[7];
    const float* cW0 = (const float*)d_in[8];
    const float* cb0 = (const float*)d_in[9];
    const float* cW1 = (const float*)d_in[10];
    const float* cb1 = (const float*)d_in[11];
    const float* cW2 = (const float*)d_in[12];
    const float* cb2 = (const float*)d_in[13];
    const float* cW3 = (const float*)d_in[14];
    const float* cb3 = (const float*)d_in[15];
    float* agg = (float*)d_ws;
    float* out = (float*)d_out;

    const size_t AGG_BYTES = (size_t)NN * HF * sizeof(float);
    unsigned short* frag = (unsigned short*)((char*)d_ws + AGG_BYTES);

    hipMemsetAsync(agg, 0, AGG_BYTES, stream);
    prep_kernel<<<(PREP_N + 255) / 256, 256, 0, stream>>>(mW0, mW1, mW2, cW0, cW1, cW2, cW3, frag);
    edge_kernel<<<EE / TE, 256, 0, stream>>>(x, ei, frag, mb0, mb1, mb2, agg);
    node_mfma<<<(NN + TN - 1) / TN, 256, 0, stream>>>(x, agg, frag, cb0, cb1, cb2, cb3, out);
}